// Round 5
// baseline (230.231 us; speedup 1.0000x reference)
//
#include <hip/hip_runtime.h>

// Pre-emphasis IIR: out[t] = y[t] + 0.85*out[t-1], shift SKIP=91, scale 32768,
// clip, astype(int16) (trunc toward zero); harness reads d_out as int32.
//
// R9 -> R10: R9's batch-load STILL never materialized (VGPR=28 < 36 needed
// for 9 live float4): with no fence the machine scheduler sank each load to
// just above its use -> 1-deep MLP again -> same 80us / 2.5 TB/s plateau
// (3rd structure in a row; fill kernels in the same capture hit 6.6 TB/s at
// 9% occupancy). R10 pins the 9-load cluster with sched_barrier(0) (loads
// cannot be scheduled across it; VGPR must rise to ~48-64 = the proof the
// batch exists), swaps NT stores for plain stores (the 6.6 TB/s fill uses
// the normal path; NT also couples store-drain into shared vmcnt waits),
// and relaxes launch_bounds to (256,6) so the live batch can't spill.
// Also: o3 == L algebraically -> iv.x = cvt16(p), one less shfl+FMA/chunk.

#define BLOCK   256
#define SKIP    91
#define COEF    0.85f
#define CHUNK_N 256                  // elements per wave chunk (64 lanes x 4)
#define CHUNKS  8                    // main chunks per wave (batch-loaded)
#define SEG     (CHUNKS * CHUNK_N)   // 2048 outputs per wave
#define WPB     (BLOCK / 64)         // 4 waves per block
#define TILE    (WPB * SEG)          // 8192 outputs per block

typedef int v4i __attribute__((ext_vector_type(4)));

__device__ __forceinline__ int cvt16(float v) {
    float s = v * 32768.f;
    s = fminf(fmaxf(s, -32768.f), 32767.f);   // fuses to v_med3_f32
    return (int)s;                            // trunc toward zero
}

__device__ __forceinline__ float4 ld_guard(const float* __restrict__ sig,
                                           long yb, long n) {
    float4 x;
    x.x = (yb + 0 >= 0 && yb + 0 < n) ? sig[yb + 0] : 0.f;
    x.y = (yb + 1 >= 0 && yb + 1 < n) ? sig[yb + 1] : 0.f;
    x.z = (yb + 2 >= 0 && yb + 2 < n) ? sig[yb + 2] : 0.f;
    x.w = (yb + 3 >= 0 && yb + 3 < n) ? sig[yb + 3] : 0.f;
    return x;
}

template <bool FAST>
__device__ __forceinline__ void run_seg(const float* __restrict__ sig,
                                        int* __restrict__ out,
                                        long segBase, long ln, int lane) {
    // scan-step multipliers: c^(4*2^d) — compile-time constants.
    const float K1  = COEF * COEF * COEF * COEF;   // c^4
    const float K2  = K1 * K1;                      // c^8
    const float K4  = K2 * K2;                      // c^16
    const float K8  = K4 * K4;                      // c^32
    const float K16 = K8 * K8;                      // c^64
    // (d=32 step weight c^128 ~ 9e-10: below fp32 noise — dropped)
    const float C1 = COEF, C2 = COEF * COEF, C3 = C2 * COEF;
    // per-lane carry weight c^(4*(lane+1))
    const float wpow = exp2f((float)(lane + 1) * (4.0f * -0.23446525109f)); // log2(0.85)

    float s0, s1, s2, s3;
    // wave scan: t[i] = IIR value at lane i elem3 from zero state at window
    // start; also leaves the lane-local inclusive scan in s0..s3.
    auto wscan = [&](const float4& x) -> float {
        s0 = x.x;
        s1 = fmaf(s0, COEF, x.y);
        s2 = fmaf(s1, COEF, x.z);
        s3 = fmaf(s2, COEF, x.w);
        float t = s3, u;
        u = __shfl_up(t, 1, 64);  t = (lane >= 1)  ? fmaf(u, K1,  t) : t;
        u = __shfl_up(t, 2, 64);  t = (lane >= 2)  ? fmaf(u, K2,  t) : t;
        u = __shfl_up(t, 4, 64);  t = (lane >= 4)  ? fmaf(u, K4,  t) : t;
        u = __shfl_up(t, 8, 64);  t = (lane >= 8)  ? fmaf(u, K8,  t) : t;
        u = __shfl_up(t, 16, 64); t = (lane >= 16) ? fmaf(u, K16, t) : t;
        return t;
    };

    // ---- Batch-issue ALL loads: warm chunk + CHUNKS main chunks.
    float4 xw, xs[CHUNKS];
    if constexpr (FAST) {
        const float* base = sig + segBase + 4 * (long)lane;   // 16B-aligned
        xw = *reinterpret_cast<const float4*>(base - 164);
#pragma unroll
        for (int c = 0; c < CHUNKS; ++c)
            xs[c] = *reinterpret_cast<const float4*>(base + (SKIP + 1) + c * CHUNK_N);
        // Fence: machine scheduler may NOT sink these loads past this point.
        // This is what makes the 9-deep MLP real (R8/R9 were silently 1-deep).
        __builtin_amdgcn_sched_barrier(0);
    } else {
        xw = ld_guard(sig, segBase - 164 + 4 * (long)lane, ln);
#pragma unroll
        for (int c = 0; c < CHUNKS; ++c)
            xs[c] = ld_guard(sig, segBase + (SKIP + 1) + (long)c * CHUNK_N
                                  + 4 * (long)lane, ln);
    }

    // warm-up: y[segBase-164 .. segBase+92) -> carry at y = segBase+91.
    // Negative indices zero-filled == exact (IIR from zero state).
    float tw   = wscan(xw);
    float y_in = __shfl(tw, 63, 64);

    const long oLim = ln - SKIP;

#pragma unroll
    for (int c = 0; c < CHUNKS; ++c) {
        const long o0 = segBase + (long)c * CHUNK_N;   // chunk output base

        float t = wscan(xs[c]);
        float L = fmaf(wpow, y_in, t);        // true IIR value at this lane's elem3
        float p = __shfl_up(L, 1, 64);        // prev lane's elem3 value (= its o3)
        if (lane == 0) p = y_in;

        // outputs, realigned by SKIP%4=3: slot0 = prev lane's elem3 = cvt16(p)
        v4i iv;
        iv.x = cvt16(p);
        iv.y = cvt16(fmaf(p, C1, s0));
        iv.z = cvt16(fmaf(p, C2, s1));
        iv.w = cvt16(fmaf(p, C3, s2));

        y_in = __shfl(L, 63, 64);             // carry for next chunk

        const long ob = o0 + 4 * (long)lane;
        if constexpr (FAST) {
            *reinterpret_cast<v4i*>(out + ob) = iv;   // plain store (NT removed)
        } else {
            if (ob + 0 >= oLim) iv.x = 0;     // zero-pad tail outputs
            if (ob + 1 >= oLim) iv.y = 0;
            if (ob + 2 >= oLim) iv.z = 0;
            if (ob + 3 >= oLim) iv.w = 0;
            if (ob + 0 < ln) out[ob + 0] = iv.x;
            if (ob + 1 < ln) out[ob + 1] = iv.y;
            if (ob + 2 < ln) out[ob + 2] = iv.z;
            if (ob + 3 < ln) out[ob + 3] = iv.w;
        }
    }
}

__global__ __launch_bounds__(BLOCK, 6) void preemph_kernel(
        const float* __restrict__ sig, int* __restrict__ out, int n) {
    const long ln   = n;
    const int  lane = threadIdx.x & 63;
    const long segBase = (long)blockIdx.x * TILE + (long)(threadIdx.x >> 6) * SEG;
    if (segBase >= ln) return;

    // fast iff: warm reads >= 0  AND  loads end <= n  AND  no output zeroing.
    const bool fast = (segBase >= 164) && (segBase + SEG + SKIP + 1 <= ln);
    if (fast) run_seg<true >(sig, out, segBase, ln, lane);
    else      run_seg<false>(sig, out, segBase, ln, lane);
}

extern "C" void kernel_launch(void* const* d_in, const int* in_sizes, int n_in,
                              void* d_out, int out_size, void* d_ws, size_t ws_size,
                              hipStream_t stream) {
    const float* sig = (const float*)d_in[0];
    int* out = (int*)d_out;
    int n = in_sizes[0];
    int grid = (int)(((long)n + TILE - 1) / TILE);
    preemph_kernel<<<grid, BLOCK, 0, stream>>>(sig, out, n);
}